// Round 17
// baseline (124.648 us; speedup 1.0000x reference)
//
#include <hip/hip_runtime.h>
#include <stdint.h>

// Problem constants (fixed by the reference)
#define BATCH   4096
#define IN_DIM  1024
#define OUT_DIM 1024

typedef __bf16 bf16x8 __attribute__((ext_vector_type(8)));
typedef float  f32x4  __attribute__((ext_vector_type(4)));

// fp32 -> bf16 bits, round-to-nearest-even
__device__ __forceinline__ uint16_t f2bf(float f) {
    union { float f; uint32_t u; } v; v.f = f;
    uint32_t u = v.u;
    uint32_t r = (u + 0x7FFFu + ((u >> 16) & 1u)) >> 16;
    return (uint16_t)r;
}

__device__ __forceinline__ float bf2f(uint16_t h) {
    union { uint32_t u; float f; } v; v.u = ((uint32_t)h) << 16;
    return v.f;
}

__device__ __forceinline__ ushort4 cvt4(float4 v) {
    ushort4 o;
    o.x = f2bf(v.x); o.y = f2bf(v.y); o.z = f2bf(v.z); o.w = f2bf(v.w);
    return o;
}

// ---------------------------------------------------------------------------
// prep: R11 verified (2048 blocks, 4x work per block).
// ---------------------------------------------------------------------------
__global__ __launch_bounds__(256) void prep(
    const float* __restrict__ x, const float* __restrict__ phase,
    const float* __restrict__ basis, const float* __restrict__ W,
    uint16_t* __restrict__ xb, uint16_t* __restrict__ Wb,
    float* __restrict__ alphaWS)
{
    const int bid = blockIdx.x;
    const int tid = threadIdx.x;

    if (bid < 1024) {
        const int r0 = bid * 4;
        if (tid < 16) {
            const int r = r0 + (tid >> 2), c = tid & 3;
            const float HALF_PI = 1.5707963267948966f;
            float s  = phase[r] / HALF_PI;
            int   q  = (int)floorf(s);
            q = q < 0 ? 0 : (q > 3 ? 3 : q);
            float t  = s - (float)q;
            float t2 = t * t, t3 = t2 * t;
            // CPI[q][k] = (q+k+3)%4  =>  alpha[c] = coef[(c - q + 1) & 3]
            const int j = (c - q + 1) & 3;
            alphaWS[r * 4 + c] = t3 * basis[j] + t2 * basis[4 + j]
                               + t * basis[8 + j] + basis[12 + j];
        }
        const float4* xs = (const float4*)(x + (size_t)r0 * IN_DIM);
        ushort4*      xd = (ushort4*)(xb + (size_t)r0 * IN_DIM);
#pragma unroll
        for (int j = 0; j < 4; ++j)
            xd[j * 256 + tid] = cvt4(xs[j * 256 + tid]);
    } else {
        const size_t j0 = (size_t)(bid - 1024) * 1024;   // of 1M float4s
        const float4* ws = (const float4*)W;
        ushort4*      wd = (ushort4*)Wb;
#pragma unroll
        for (int j = 0; j < 4; ++j)
            wd[j0 + j * 256 + tid] = cvt4(ws[j0 + j * 256 + tid]);
    }
}

// ---------------------------------------------------------------------------
// gemm_fused: R14 structure (best passing: 45.0 us gemm / 123.46 total —
// 128M x 64N, 4 waves, wave wid = control point c, acc[8][4], in-block
// c-reduction) + B-only double buffer using ONLY __syncthreads barriers.
//
// R16 lesson: raw s_barrier + counted vmcnt RACES under graph replay (first
// launch passed, post-timing diverged) — m152's "naive combination races".
// This variant is race-free by construction: every barrier is __syncthreads,
// whose compiler-emitted s_waitcnt vmcnt(0) lgkmcnt(0) drain guarantees
// staging visibility; no ordering depends on hand-placed waits.
//
// Per K-step:
//   __syncthreads();            // As(kt) + Bs[cur](kt) staged (drained)
//   STAGE_B(cur^1, kt+1);       // 8 loads fly UNDER the 64-MFMA phase
//   compute(As, Bs[cur]);       // 64 MFMA + ds_reads
//   __syncthreads();            // all reads done (+ drains B residual)
//   STAGE_A(kt+1);              // 4 loads into single A buffer (WAR-safe:
//                               //  all As reads completed at the barrier)
// vs R14 (all 12 loads issued at top, fully exposed): 8/12 loads now
// overlap compute; A's exposure is short (L2-hot panel, 16-block reuse).
// LDS: As 16KB + Bs 2x32KB = 80KB -> 2 blocks/CU = exactly the 512-block
// grid's occupancy (no loss, unlike R8's 64x64 dbuf).
// Geometry / swizzle / K-order / epilogue byte-identical to R14.
// ---------------------------------------------------------------------------
#define PS 66   // padded row stride (elems) for epilogue exchange

__global__ __launch_bounds__(256, 2) void gemm_fused(
    const uint16_t* __restrict__ xb, const uint16_t* __restrict__ Wb,
    const float* __restrict__ alphaWS, const float* __restrict__ biases,
    float* __restrict__ out)
{
    __shared__ uint16_t lds[8192 + 2 * 16384];   // As 16KB | Bs dbuf 64KB = 80KB
    uint16_t* As = lds;                          // [128][64]
    uint16_t* Ps = lds;                          // epilogue alias [4][64][PS]

    const int tid  = threadIdx.x;
    const int lane = tid & 63;
    const int wid  = tid >> 6;        // = c for this wave
    const int tileM = blockIdx.x * 128;
    const int tileN = blockIdx.y * 64;

    f32x4 acc[8][4];
#pragma unroll
    for (int mi = 0; mi < 8; ++mi)
#pragma unroll
        for (int ni = 0; ni < 4; ++ni)
            acc[mi][ni] = (f32x4){0.f, 0.f, 0.f, 0.f};

    // staging: slice = 8 rows x 64 cols; lane l -> row l>>3, phys chunk l&7,
    // source global chunk = (l&7) ^ (l>>3)   (XOR swizzle, round-0 verified)
    const int srow = lane >> 3;
    const int gchunk = ((lane & 7) ^ srow) * 8;

    const uint16_t* Ag = xb + (size_t)tileM * 1024;
    const uint16_t* Bg = Wb + ((size_t)wid << 20) + (size_t)tileN * 1024;

    const int quad = lane >> 4;
    const int l7   = lane & 7;
    const int l15  = lane & 15;

    // A: 16 slices (128 rows), wave stages 4 — shared by all 4 waves
    auto STAGE_A = [&](int kt) {
        const int k0 = kt * 64;
#pragma unroll
        for (int j = 0; j < 4; ++j) {
            const int s = wid * 4 + j;
            const uint16_t* ga = Ag + (size_t)(s * 8 + srow) * 1024 + k0 + gchunk;
            __builtin_amdgcn_global_load_lds(
                (const __attribute__((address_space(1))) void*)ga,
                (__attribute__((address_space(3))) void*)(As + s * 512), 16, 0, 0);
        }
    };
    // B_c: 8 slices into buffer buf, this wave's own control point
    auto STAGE_B = [&](int buf, int kt) {
        const int k0 = kt * 64;
        uint16_t* Bsb = lds + 8192 + buf * 16384;
#pragma unroll
        for (int j = 0; j < 8; ++j) {
            const uint16_t* gb = Bg + (size_t)(j * 8 + srow) * 1024 + k0 + gchunk;
            __builtin_amdgcn_global_load_lds(
                (const __attribute__((address_space(1))) void*)gb,
                (__attribute__((address_space(3))) void*)(Bsb + wid * 4096 + j * 512), 16, 0, 0);
        }
    };

    STAGE_A(0);
    STAGE_B(0, 0);
    int cur = 0;

    for (int kt = 0; kt < 16; ++kt) {
        __syncthreads();                         // As(kt)+Bs[cur](kt) staged;
                                                 // prev buffers' reads done
        if (kt < 15) STAGE_B(cur ^ 1, kt + 1);   // flies under the MFMA phase

        const uint16_t* Bsb = lds + 8192 + cur * 16384;
#pragma unroll
        for (int ks = 0; ks < 2; ++ks) {
            const int ch = (ks * 4 + quad) ^ l7;          // physical chunk
            bf16x8 bfr[4];
#pragma unroll
            for (int ni = 0; ni < 4; ++ni)
                bfr[ni] = *(const bf16x8*)(Bsb + wid * 4096 + (ni * 16 + l15) * 64 + ch * 8);
#pragma unroll
            for (int mi = 0; mi < 8; ++mi) {
                bf16x8 af = *(const bf16x8*)(As + (mi * 16 + l15) * 64 + ch * 8);
#pragma unroll
                for (int ni = 0; ni < 4; ++ni)
                    acc[mi][ni] = __builtin_amdgcn_mfma_f32_16x16x32_bf16(
                        af, bfr[ni], acc[mi][ni], 0, 0, 0);
            }
        }

        __syncthreads();                         // all As/Bs[cur] reads done
        if (kt < 15) STAGE_A(kt + 1);            // A single-buffer now WAR-safe
        cur ^= 1;
    }

    // ---- epilogue: in-block c-reduction (R6/R14 verified), one m-half per phase ----
    // C/D layout: col = lane&15, row(64-sub-tile) = mi'*16 + quad*4 + r.
#pragma unroll
    for (int p = 0; p < 2; ++p) {
        __syncthreads();               // staging/Ps region quiescent
        // 1) publish alpha-scaled bf16 partials for rows p*64 .. p*64+63
#pragma unroll
        for (int mi = 0; mi < 4; ++mi) {
#pragma unroll
            for (int r = 0; r < 4; ++r) {
                const int row = mi * 16 + quad * 4 + r;
                const float a = alphaWS[(size_t)(tileM + p * 64 + row) * 4 + wid];
#pragma unroll
                for (int ni = 0; ni < 4; ++ni)
                    Ps[wid * (64 * PS) + row * PS + ni * 16 + l15] =
                        f2bf(a * acc[p * 4 + mi][ni][r]);
            }
        }
        __syncthreads();

        // 2) combine: thread t -> row rr = t>>2, 16-col group cg = t&3
        const int rr = tid >> 2;
        const int cg = tid & 3;
        const int colb = cg * 16;
        const int m = tileM + p * 64 + rr;
        const float4 al = *(const float4*)(alphaWS + (size_t)m * 4);
        const float a[4] = {al.x, al.y, al.z, al.w};

        float res[16];
#pragma unroll
        for (int j = 0; j < 16; ++j) res[j] = 0.f;

#pragma unroll
        for (int cc = 0; cc < 4; ++cc) {
            // alpha-weighted bias (bias is L2-hot, 16KB total)
#pragma unroll
            for (int jj = 0; jj < 4; ++jj) {
                float4 bv = *(const float4*)(biases + (size_t)cc * OUT_DIM + tileN + colb + jj * 4);
                res[jj * 4 + 0] += a[cc] * bv.x;
                res[jj * 4 + 1] += a[cc] * bv.y;
                res[jj * 4 + 2] += a[cc] * bv.z;
                res[jj * 4 + 3] += a[cc] * bv.w;
            }
            // partial (ushort2 = 4B aligned: offsets all even)
            const uint16_t* pp = Ps + cc * (64 * PS) + rr * PS + colb;
#pragma unroll
            for (int jj = 0; jj < 8; ++jj) {
                uint32_t pv = *(const uint32_t*)(pp + jj * 2);
                res[jj * 2 + 0] += bf2f((uint16_t)(pv & 0xFFFFu));
                res[jj * 2 + 1] += bf2f((uint16_t)(pv >> 16));
            }
        }

        float* orow = out + (size_t)m * OUT_DIM + tileN + colb;
#pragma unroll
        for (int jj = 0; jj < 4; ++jj) {
            float4 o = {res[jj * 4 + 0], res[jj * 4 + 1], res[jj * 4 + 2], res[jj * 4 + 3]};
            *(float4*)(orow + jj * 4) = o;
        }
    }
}

extern "C" void kernel_launch(void* const* d_in, const int* in_sizes, int n_in,
                              void* d_out, int out_size, void* d_ws, size_t ws_size,
                              hipStream_t stream)
{
    const float* x       = (const float*)d_in[0];  // (B, IN)
    const float* phase   = (const float*)d_in[1];  // (B,)
    const float* weights = (const float*)d_in[2];  // (4, OUT, IN)
    const float* biases  = (const float*)d_in[3];  // (4, OUT)
    const float* basis   = (const float*)d_in[4];  // (4, 4)
    float* out = (float*)d_out;                    // (B, OUT)

    // Workspace: xb bf16 8 MB | Wb bf16 8 MB | alpha 64 KB
    uint16_t* xb = (uint16_t*)d_ws;
    uint16_t* Wb = xb + (size_t)BATCH * IN_DIM;
    float* alphaWS = (float*)(Wb + (size_t)4 * OUT_DIM * IN_DIM);

    prep<<<2048, 256, 0, stream>>>(x, phase, basis, weights, xb, Wb, alphaWS);

    dim3 grid(BATCH / 128, OUT_DIM / 64);  // 512 blocks, M-fastest (default
                                           // order: panel-sharers contemporaneous)
    gemm_fused<<<grid, 256, 0, stream>>>(xb, Wb, alphaWS, biases, out);
}

// Round 18
// 123.536 us; speedup vs baseline: 1.0090x; 1.0090x over previous
//
#include <hip/hip_runtime.h>
#include <stdint.h>

// Problem constants (fixed by the reference)
#define BATCH   4096
#define IN_DIM  1024
#define OUT_DIM 1024

typedef __bf16 bf16x8 __attribute__((ext_vector_type(8)));
typedef float  f32x4  __attribute__((ext_vector_type(4)));

// fp32 -> bf16 bits, round-to-nearest-even
__device__ __forceinline__ uint16_t f2bf(float f) {
    union { float f; uint32_t u; } v; v.f = f;
    uint32_t u = v.u;
    uint32_t r = (u + 0x7FFFu + ((u >> 16) & 1u)) >> 16;
    return (uint16_t)r;
}

__device__ __forceinline__ float bf2f(uint16_t h) {
    union { uint32_t u; float f; } v; v.u = ((uint32_t)h) << 16;
    return v.f;
}

__device__ __forceinline__ ushort4 cvt4(float4 v) {
    ushort4 o;
    o.x = f2bf(v.x); o.y = f2bf(v.y); o.z = f2bf(v.z); o.w = f2bf(v.w);
    return o;
}

// ---------------------------------------------------------------------------
// prep: R11 verified (2048 blocks, 4x work per block).
// ---------------------------------------------------------------------------
__global__ __launch_bounds__(256) void prep(
    const float* __restrict__ x, const float* __restrict__ phase,
    const float* __restrict__ basis, const float* __restrict__ W,
    uint16_t* __restrict__ xb, uint16_t* __restrict__ Wb,
    float* __restrict__ alphaWS)
{
    const int bid = blockIdx.x;
    const int tid = threadIdx.x;

    if (bid < 1024) {
        const int r0 = bid * 4;
        if (tid < 16) {
            const int r = r0 + (tid >> 2), c = tid & 3;
            const float HALF_PI = 1.5707963267948966f;
            float s  = phase[r] / HALF_PI;
            int   q  = (int)floorf(s);
            q = q < 0 ? 0 : (q > 3 ? 3 : q);
            float t  = s - (float)q;
            float t2 = t * t, t3 = t2 * t;
            // CPI[q][k] = (q+k+3)%4  =>  alpha[c] = coef[(c - q + 1) & 3]
            const int j = (c - q + 1) & 3;
            alphaWS[r * 4 + c] = t3 * basis[j] + t2 * basis[4 + j]
                               + t * basis[8 + j] + basis[12 + j];
        }
        const float4* xs = (const float4*)(x + (size_t)r0 * IN_DIM);
        ushort4*      xd = (ushort4*)(xb + (size_t)r0 * IN_DIM);
#pragma unroll
        for (int j = 0; j < 4; ++j)
            xd[j * 256 + tid] = cvt4(xs[j * 256 + tid]);
    } else {
        const size_t j0 = (size_t)(bid - 1024) * 1024;   // of 1M float4s
        const float4* ws = (const float4*)W;
        ushort4*      wd = (ushort4*)Wb;
#pragma unroll
        for (int j = 0; j < 4; ++j)
            wd[j0 + j * 256 + tid] = cvt4(ws[j0 + j * 256 + tid]);
    }
}

// ---------------------------------------------------------------------------
// gemm_fused: R14 VERBATIM — the session's best passing configuration
// (123.46 us total; gemm 45.0 us = 765 TF).
// 128M x 64N tile, 4 waves / 256 threads, wave wid = control point c: each
// wave computes the full 128x64 for its c (acc[8][4]). Staged per K-step:
// A 16KB (shared x4 waves) + B 32KB (c-private) = 187 B/MFMA. Single-buffer,
// 2 __syncthreads per K-step.
// This basin survived A/B against every structural variant tried:
//   64x64 4-wave (R6: 46.6us), 8-wave 128x64 (R7: 90us), dbuf+syncthreads
//   @64^2 (R8: 49us), B-direct-from-global (R9: 84us), inline-f32-staging
//   (R10: 110us), BK=32 counted-vmcnt (R12: 65us, 9x bank conflicts),
//   XCD remap (R13: 60us, L2 locality destroyed), raw-barrier counted-vmcnt
//   (R16: RACES under graph replay), B-dbuf+syncthreads (R17: 55us — the
//   barrier's vmcnt(0) drain re-exposes the prefetch, guide m97/m99 stall).
// Cross-block coherence refuted 4 ways (R2-R5). The only known path past
// ~45us is the 8-phase counted-vmcnt schedule, which cannot be certified
// race-free under this harness's graph replay (R16 evidence + m152).
// Epilogue: in-block c-reduction via Ps LDS exchange, one m-half per phase.
// ---------------------------------------------------------------------------
#define PS 66   // padded row stride (elems) for epilogue exchange

__global__ __launch_bounds__(256, 2) void gemm_fused(
    const uint16_t* __restrict__ xb, const uint16_t* __restrict__ Wb,
    const float* __restrict__ alphaWS, const float* __restrict__ biases,
    float* __restrict__ out)
{
    __shared__ uint16_t lds[128 * 64 + 4 * 64 * 64];  // As 16KB | Bs 32KB (48KB)
    uint16_t* As = lds;                                // [128][64]
    uint16_t* Bs = lds + 8192;                         // [4][64][64]
    uint16_t* Ps = lds;                                // epilogue alias [4][64][PS]

    const int tid  = threadIdx.x;
    const int lane = tid & 63;
    const int wid  = tid >> 6;        // = c for this wave
    const int tileM = blockIdx.x * 128;
    const int tileN = blockIdx.y * 64;

    f32x4 acc[8][4];
#pragma unroll
    for (int mi = 0; mi < 8; ++mi)
#pragma unroll
        for (int ni = 0; ni < 4; ++ni)
            acc[mi][ni] = (f32x4){0.f, 0.f, 0.f, 0.f};

    // staging: slice = 8 rows x 64 cols; lane l -> row l>>3, phys chunk l&7,
    // source global chunk = (l&7) ^ (l>>3)   (XOR swizzle, round-0 verified)
    const int srow = lane >> 3;
    const int gchunk = ((lane & 7) ^ srow) * 8;

    const uint16_t* Ag = xb + (size_t)tileM * 1024;
    const uint16_t* Bg = Wb + ((size_t)wid << 20) + (size_t)tileN * 1024;

    const int quad = lane >> 4;
    const int l7   = lane & 7;
    const int l15  = lane & 15;

    for (int kt = 0; kt < 16; ++kt) {
        const int k0 = kt * 64;
        // A: 16 slices (128 rows), wave stages 4 — shared by all 4 waves
#pragma unroll
        for (int j = 0; j < 4; ++j) {
            const int s = wid * 4 + j;
            const uint16_t* ga = Ag + (size_t)(s * 8 + srow) * 1024 + k0 + gchunk;
            __builtin_amdgcn_global_load_lds(
                (const __attribute__((address_space(1))) void*)ga,
                (__attribute__((address_space(3))) void*)(As + s * 512), 16, 0, 0);
        }
        // B_c: 8 slices, this wave's own control point
#pragma unroll
        for (int j = 0; j < 8; ++j) {
            const uint16_t* gb = Bg + (size_t)(j * 8 + srow) * 1024 + k0 + gchunk;
            __builtin_amdgcn_global_load_lds(
                (const __attribute__((address_space(1))) void*)gb,
                (__attribute__((address_space(3))) void*)(Bs + wid * 4096 + j * 512), 16, 0, 0);
        }
        __syncthreads();

#pragma unroll
        for (int ks = 0; ks < 2; ++ks) {
            const int ch = (ks * 4 + quad) ^ l7;       // physical chunk
            bf16x8 bfr[4];
#pragma unroll
            for (int ni = 0; ni < 4; ++ni)
                bfr[ni] = *(const bf16x8*)(Bs + wid * 4096 + (ni * 16 + l15) * 64 + ch * 8);
#pragma unroll
            for (int mi = 0; mi < 8; ++mi) {
                bf16x8 af = *(const bf16x8*)(As + (mi * 16 + l15) * 64 + ch * 8);
#pragma unroll
                for (int ni = 0; ni < 4; ++ni)
                    acc[mi][ni] = __builtin_amdgcn_mfma_f32_16x16x32_bf16(
                        af, bfr[ni], acc[mi][ni], 0, 0, 0);
            }
        }
        __syncthreads();
    }

    // ---- epilogue: in-block c-reduction (R6 verified), one m-half per phase ----
    // C/D layout: col = lane&15, row(64-sub-tile) = mi'*16 + quad*4 + r.
#pragma unroll
    for (int p = 0; p < 2; ++p) {
        __syncthreads();               // staging/Ps region quiescent
        // 1) publish alpha-scaled bf16 partials for rows p*64 .. p*64+63
#pragma unroll
        for (int mi = 0; mi < 4; ++mi) {
#pragma unroll
            for (int r = 0; r < 4; ++r) {
                const int row = mi * 16 + quad * 4 + r;
                const float a = alphaWS[(size_t)(tileM + p * 64 + row) * 4 + wid];
#pragma unroll
                for (int ni = 0; ni < 4; ++ni)
                    Ps[wid * (64 * PS) + row * PS + ni * 16 + l15] =
                        f2bf(a * acc[p * 4 + mi][ni][r]);
            }
        }
        __syncthreads();

        // 2) combine: thread t -> row rr = t>>2, 16-col group cg = t&3
        const int rr = tid >> 2;
        const int cg = tid & 3;
        const int colb = cg * 16;
        const int m = tileM + p * 64 + rr;
        const float4 al = *(const float4*)(alphaWS + (size_t)m * 4);
        const float a[4] = {al.x, al.y, al.z, al.w};

        float res[16];
#pragma unroll
        for (int j = 0; j < 16; ++j) res[j] = 0.f;

#pragma unroll
        for (int cc = 0; cc < 4; ++cc) {
            // alpha-weighted bias (bias is L2-hot, 16KB total)
#pragma unroll
            for (int jj = 0; jj < 4; ++jj) {
                float4 bv = *(const float4*)(biases + (size_t)cc * OUT_DIM + tileN + colb + jj * 4);
                res[jj * 4 + 0] += a[cc] * bv.x;
                res[jj * 4 + 1] += a[cc] * bv.y;
                res[jj * 4 + 2] += a[cc] * bv.z;
                res[jj * 4 + 3] += a[cc] * bv.w;
            }
            // partial (ushort2 = 4B aligned: offsets all even)
            const uint16_t* pp = Ps + cc * (64 * PS) + rr * PS + colb;
#pragma unroll
            for (int jj = 0; jj < 8; ++jj) {
                uint32_t pv = *(const uint32_t*)(pp + jj * 2);
                res[jj * 2 + 0] += bf2f((uint16_t)(pv & 0xFFFFu));
                res[jj * 2 + 1] += bf2f((uint16_t)(pv >> 16));
            }
        }

        float* orow = out + (size_t)m * OUT_DIM + tileN + colb;
#pragma unroll
        for (int jj = 0; jj < 4; ++jj) {
            float4 o = {res[jj * 4 + 0], res[jj * 4 + 1], res[jj * 4 + 2], res[jj * 4 + 3]};
            *(float4*)(orow + jj * 4) = o;
        }
    }
}

extern "C" void kernel_launch(void* const* d_in, const int* in_sizes, int n_in,
                              void* d_out, int out_size, void* d_ws, size_t ws_size,
                              hipStream_t stream)
{
    const float* x       = (const float*)d_in[0];  // (B, IN)
    const float* phase   = (const float*)d_in[1];  // (B,)
    const float* weights = (const float*)d_in[2];  // (4, OUT, IN)
    const float* biases  = (const float*)d_in[3];  // (4, OUT)
    const float* basis   = (const float*)d_in[4];  // (4, 4)
    float* out = (float*)d_out;                    // (B, OUT)

    // Workspace: xb bf16 8 MB | Wb bf16 8 MB | alpha 64 KB
    uint16_t* xb = (uint16_t*)d_ws;
    uint16_t* Wb = xb + (size_t)BATCH * IN_DIM;
    float* alphaWS = (float*)(Wb + (size_t)4 * OUT_DIM * IN_DIM);

    prep<<<2048, 256, 0, stream>>>(x, phase, basis, weights, xb, Wb, alphaWS);

    dim3 grid(BATCH / 128, OUT_DIM / 64);  // 512 blocks, M-fastest (default
                                           // order: panel-sharers contemporaneous)
    gemm_fused<<<grid, 256, 0, stream>>>(xb, Wb, alphaWS, biases, out);
}